// Round 4
// baseline (272.693 us; speedup 1.0000x reference)
//
#include <hip/hip_runtime.h>
#include <math.h>

#define M     1024
#define NB    16
#define NC    32
#define HF    256
#define WF    256
#define RH    8
#define MAXW  128
#define OUT0  (M * RH * MAXW * NC)   // 33,554,432 floats

typedef float    f4raw __attribute__((ext_vector_type(4)));  // nontemporal-store-compatible
typedef _Float16 h4    __attribute__((ext_vector_type(4)));
typedef _Float16 h8    __attribute__((ext_vector_type(8)));

struct BoxParam {
    float p1x, p1y;   // top-left corner (already /4)
    float axx, axy;   // per-x step
    float ayx, ayy;   // per-y step
    int   width;      // clipped int width
    int   n;          // feature-map batch index
};

// Geometry + exact width (must match numpy bit-exactly: no FMA contraction).
__device__ __forceinline__ int box_geom(
    const float* __restrict__ boxes, int i,
    float& x1, float& y1, float& dwx, float& dwy,
    float& dhx, float& dhy, float& wf)
{
    x1 = boxes[i * 8 + 0] * 0.25f; y1 = boxes[i * 8 + 1] * 0.25f;
    float x2 = boxes[i * 8 + 2] * 0.25f, y2 = boxes[i * 8 + 3] * 0.25f;
    float x4 = boxes[i * 8 + 6] * 0.25f, y4 = boxes[i * 8 + 7] * 0.25f;
    dwx = x2 - x1; dwy = y2 - y1;
    dhx = x4 - x1; dhy = y4 - y1;
    float bw2   = __fadd_rn(__fmul_rn(dwx, dwx), __fmul_rn(dwy, dwy));
    float bh2   = __fadd_rn(__fmul_rn(dhx, dhx), __fmul_rn(dhy, dhy));
    float box_w = __fsqrt_rn(bw2);
    float box_h = __fsqrt_rn(bh2);
    bool  swp = (box_w <= box_h);
    float bwv = swp ? box_h : box_w;
    float bhv = swp ? box_w : box_h;
    float ratio = __fdiv_rn(__fmul_rn(8.0f, bwv), fmaxf(bhv, 1e-6f));
    wf = fminf(fmaxf(ceilf(ratio), 1.0f), 128.0f);
    return (int)wf;
}

// ---------------------------------------------------------------------------
// Setup: 16 blocks x 256 threads; block b ranks boxes [b*64, b*64+64) with
// 4 threads per box, shuffle-reduced. Stable descending sort by width.
// ---------------------------------------------------------------------------
__global__ __launch_bounds__(256) void roi_setup_kernel(
    const float* __restrict__ boxes, const int* __restrict__ mapping,
    BoxParam* __restrict__ params, float* __restrict__ out_tail)
{
    __shared__ int s_w[M];
    const int t = threadIdx.x, b = blockIdx.x;

    #pragma unroll
    for (int r = 0; r < 4; ++r) {
        int i = r * 256 + t;
        float x1, y1, dwx, dwy, dhx, dhy, wf;
        s_w[i] = box_geom(boxes, i, x1, y1, dwx, dwy, dhx, dhy, wf);
    }
    __syncthreads();

    const int local = t >> 2;
    const int q     = t & 3;
    const int i     = b * 64 + local;
    const int w     = s_w[i];

    const int4* sw4 = (const int4*)(s_w + q * 256);
    int rank = 0;
    for (int j4 = 0; j4 < 64; ++j4) {
        int4 v = sw4[j4];
        int  j = q * 256 + j4 * 4;
        rank += (v.x > w) || ((v.x == w) && (j + 0 < i));
        rank += (v.y > w) || ((v.y == w) && (j + 1 < i));
        rank += (v.z > w) || ((v.z == w) && (j + 2 < i));
        rank += (v.w > w) || ((v.w == w) && (j + 3 < i));
    }
    rank += __shfl_down(rank, 1);
    rank += __shfl_down(rank, 2);

    if (q == 0) {
        float x1, y1, dwx, dwy, dhx, dhy, wf;
        box_geom(boxes, i, x1, y1, dwx, dwy, dhx, dhy, wf);
        BoxParam bp;
        bp.p1x = x1; bp.p1y = y1;
        bp.axx = __fdiv_rn(dwx, wf);  bp.axy = __fdiv_rn(dwy, wf);
        bp.ayx = dhx * 0.125f;        bp.ayy = dhy * 0.125f;
        bp.width = w;
        bp.n     = mapping[i];
        params[rank] = bp;
        out_tail[rank]     = wf;
        out_tail[M + rank] = (float)i;
    }
}

// ---------------------------------------------------------------------------
// Transpose NCHW fp32 -> NHWC fp16, NO LDS / NO barrier: in-register 8x8.
// Block = (n, 8-row y-group), 256 threads = 8 x-octets x 4 channel-quads x
// 8 y-rows; loops 4 x-tiles of 64. Each thread: 16 dwordx4 loads (8 channel
// rows x 32 B), register transpose (free), 64 RTN cvts, 8 h8 stores.
// Grid = 16 * 32 = 512 blocks. All register indices compile-time constant.
// ---------------------------------------------------------------------------
__global__ __launch_bounds__(256) void roi_transpose_kernel(
    const float* __restrict__ fm, _Float16* __restrict__ fmT)
{
    const int t  = threadIdx.x;
    const int xg = t & 7;            // x-octet within 64-wide tile
    const int cq = (t >> 3) & 3;     // channel quad -> 8 channels
    const int yl = t >> 5;           // 0..7
    const int c8 = cq * 8;
    const int x0 = xg * 8;

    const int n  = blockIdx.x >> 5;          // 0..15
    const int y  = (blockIdx.x & 31) * 8 + yl;

    const float* cbase = fm + ((size_t)(n * NC + c8) * HF + y) * WF;
    _Float16*    obase = fmT + ((size_t)(n * HF + y) * WF) * NC + c8;

    for (int xt = 0; xt < 4; ++xt) {
        const int xb = xt * 64 + x0;
        float r[8][8];
        #pragma unroll
        for (int i = 0; i < 8; ++i) {
            const float* rp = cbase + (size_t)i * (HF * WF) + xb;
            float4 lo = ((const float4*)rp)[0];
            float4 hi = ((const float4*)rp)[1];
            r[i][0] = lo.x; r[i][1] = lo.y; r[i][2] = lo.z; r[i][3] = lo.w;
            r[i][4] = hi.x; r[i][5] = hi.y; r[i][6] = hi.z; r[i][7] = hi.w;
        }
        #pragma unroll
        for (int j = 0; j < 8; ++j) {
            h8 hv;
            #pragma unroll
            for (int i = 0; i < 8; ++i)
                hv[i] = (_Float16)r[i][j];
            *(h8*)(obase + (size_t)(xb + j) * NC) = hv;
        }
    }
}

// ---------------------------------------------------------------------------
// Main (NHWC fp16): block = (k,y) via blockIdx = y*1024+k. 1024%8==0 so all
// 8 rows of box k land on the same XCD (k%8). 256 threads = 32 x-positions
// x 8 channel-quads; a pixel's 32 channels = 64 B = ONE cache line.
// sx/sy bit-exact to numpy: (p1 + ax*x) + ay*y, no FMA contraction.
// Interpolation in fp32 after convert; output stores nontemporal.
// ---------------------------------------------------------------------------
__global__ __launch_bounds__(256) void roi_main_nhwc(
    const _Float16* __restrict__ fmT, const BoxParam* __restrict__ params,
    float* __restrict__ out)
{
    const int k = blockIdx.x & (M - 1);
    const int y = blockIdx.x >> 10;
    const BoxParam bp = params[k];     // block-uniform -> scalar loads

    const int t  = threadIdx.x;
    const int cg = (t & 7) * 4;        // channel quad
    const int xl = t >> 3;             // 0..31

    const _Float16* fmb  = fmT + (size_t)bp.n * (HF * WF * NC);
    float*          orow = out + ((size_t)(k * RH + y) * MAXW) * NC + cg;

    const float yf    = (float)y;
    const int   width = bp.width;
    const int   niter = (width + 31) >> 5;   // block-uniform trip count

    const float ayxy = __fmul_rn(bp.ayx, yf);
    const float ayyy = __fmul_rn(bp.ayy, yf);

    for (int xi = 0; xi < niter; ++xi) {
        const int x = xi * 32 + xl;
        float xf = (float)x;
        // numpy order: (p1 + ax*x) + ay*y, each op round-to-nearest
        float sx = __fadd_rn(__fadd_rn(bp.p1x, __fmul_rn(bp.axx, xf)), ayxy);
        float sy = __fadd_rn(__fadd_rn(bp.p1y, __fmul_rn(bp.axy, xf)), ayyy);
        float fx0 = floorf(sx), fy0 = floorf(sy);
        float tx = sx - fx0,    ty = sy - fy0;
        int ix0 = (int)fx0, iy0 = (int)fy0;
        int ix1 = ix0 + 1,  iy1 = iy0 + 1;

        float valid = (x < width) ? 1.0f : 0.0f;
        float mx0 = (ix0 >= 0 && ix0 < WF) ? valid : 0.0f;
        float mx1 = (ix1 >= 0 && ix1 < WF) ? valid : 0.0f;
        float my0 = (iy0 >= 0 && iy0 < HF) ? 1.0f : 0.0f;
        float my1 = (iy1 >= 0 && iy1 < HF) ? 1.0f : 0.0f;
        int xc0 = min(max(ix0, 0), WF - 1), xc1 = min(max(ix1, 0), WF - 1);
        int yc0 = min(max(iy0, 0), HF - 1), yc1 = min(max(iy1, 0), HF - 1);

        float omtx = 1.0f - tx, omty = 1.0f - ty;
        float q00 = omtx * omty * (mx0 * my0);
        float q01 = tx   * omty * (mx1 * my0);
        float q10 = omtx * ty   * (mx0 * my1);
        float q11 = tx   * ty   * (mx1 * my1);

        h4 v00 = *(const h4*)(fmb + (size_t)(yc0 * WF + xc0) * NC + cg);
        h4 v01 = *(const h4*)(fmb + (size_t)(yc0 * WF + xc1) * NC + cg);
        h4 v10 = *(const h4*)(fmb + (size_t)(yc1 * WF + xc0) * NC + cg);
        h4 v11 = *(const h4*)(fmb + (size_t)(yc1 * WF + xc1) * NC + cg);

        f4raw r;
        r.x = (float)v00[0] * q00 + (float)v01[0] * q01 + (float)v10[0] * q10 + (float)v11[0] * q11;
        r.y = (float)v00[1] * q00 + (float)v01[1] * q01 + (float)v10[1] * q10 + (float)v11[1] * q11;
        r.z = (float)v00[2] * q00 + (float)v01[2] * q01 + (float)v10[2] * q10 + (float)v11[2] * q11;
        r.w = (float)v00[3] * q00 + (float)v01[3] * q01 + (float)v10[3] * q10 + (float)v11[3] * q11;
        __builtin_nontemporal_store(r, (f4raw*)(orow + (size_t)x * NC));
    }
    // zero-fill remaining columns (col_mask; d_out is poisoned each launch)
    const f4raw z = {0.f, 0.f, 0.f, 0.f};
    for (int xi = niter; xi < MAXW / 32; ++xi) {
        const int x = xi * 32 + xl;
        __builtin_nontemporal_store(z, (f4raw*)(orow + (size_t)x * NC));
    }
}

// ---------------------------------------------------------------------------
// Fallback (NCHW direct gather, fp32) if d_ws can't hold the transposed map.
// ---------------------------------------------------------------------------
__global__ __launch_bounds__(256) void roi_main_nchw(
    const float* __restrict__ fm, const BoxParam* __restrict__ params,
    float* __restrict__ out)
{
    const int k = blockIdx.x & (M - 1);
    const int y = blockIdx.x >> 10;
    const BoxParam bp = params[k];

    const int c  = threadIdx.x & 31;
    const int xg = threadIdx.x >> 5;

    const float* fmc  = fm + ((size_t)(bp.n * NC + c)) * (size_t)(HF * WF);
    float*       orow = out + ((size_t)(k * RH + y) * MAXW) * NC + c;

    const float yf = (float)y;
    const float ayxy = __fmul_rn(bp.ayx, yf);
    const float ayyy = __fmul_rn(bp.ayy, yf);
    const int width = bp.width;
    const int niter = (width + 7) >> 3;

    for (int xi = 0; xi < niter; ++xi) {
        const int x = xi * 8 + xg;
        float xf = (float)x;
        float sx = __fadd_rn(__fadd_rn(bp.p1x, __fmul_rn(bp.axx, xf)), ayxy);
        float sy = __fadd_rn(__fadd_rn(bp.p1y, __fmul_rn(bp.axy, xf)), ayyy);
        float fx0 = floorf(sx), fy0 = floorf(sy);
        float tx = sx - fx0,    ty = sy - fy0;
        int ix0 = (int)fx0, iy0 = (int)fy0;
        int ix1 = ix0 + 1,  iy1 = iy0 + 1;
        float valid = (x < width) ? 1.0f : 0.0f;
        float mx0 = (ix0 >= 0 && ix0 < WF) ? valid : 0.0f;
        float mx1 = (ix1 >= 0 && ix1 < WF) ? valid : 0.0f;
        float my0 = (iy0 >= 0 && iy0 < HF) ? 1.0f : 0.0f;
        float my1 = (iy1 >= 0 && iy1 < HF) ? 1.0f : 0.0f;
        int xc0 = min(max(ix0, 0), WF - 1), xc1 = min(max(ix1, 0), WF - 1);
        int yc0 = min(max(iy0, 0), HF - 1), yc1 = min(max(iy1, 0), HF - 1);
        float omtx = 1.0f - tx, omty = 1.0f - ty;
        float q00 = omtx * omty * (mx0 * my0);
        float q01 = tx   * omty * (mx1 * my0);
        float q10 = omtx * ty   * (mx0 * my1);
        float q11 = tx   * ty   * (mx1 * my1);
        float val = fmc[yc0 * WF + xc0] * q00 + fmc[yc0 * WF + xc1] * q01
                  + fmc[yc1 * WF + xc0] * q10 + fmc[yc1 * WF + xc1] * q11;
        orow[(size_t)(x * NC)] = val;
    }
    for (int xi = niter; xi < 16; ++xi)
        orow[(size_t)((xi * 8 + xg) * NC)] = 0.0f;
}

// ---------------------------------------------------------------------------
extern "C" void kernel_launch(void* const* d_in, const int* in_sizes, int n_in,
                              void* d_out, int out_size, void* d_ws, size_t ws_size,
                              hipStream_t stream)
{
    const float* fm      = (const float*)d_in[0];
    const float* boxes   = (const float*)d_in[1];
    const int*   mapping = (const int*)d_in[2];
    float*       out     = (float*)d_out;

    BoxParam* params = (BoxParam*)d_ws;                       // 32 KB
    const size_t FMT_OFF = 65536;
    const size_t need = FMT_OFF + (size_t)NB * HF * WF * NC * sizeof(_Float16);

    roi_setup_kernel<<<16, 256, 0, stream>>>(boxes, mapping, params, out + OUT0);

    if (ws_size >= need) {
        _Float16* fmT = (_Float16*)((char*)d_ws + FMT_OFF);
        roi_transpose_kernel<<<NB * 32, 256, 0, stream>>>(fm, fmT);
        roi_main_nhwc<<<M * RH, 256, 0, stream>>>(fmT, params, out);
    } else {
        roi_main_nchw<<<M * RH, 256, 0, stream>>>(fm, params, out);
    }
}

// Round 8
// 259.201 us; speedup vs baseline: 1.0521x; 1.0521x over previous
//
#include <hip/hip_runtime.h>
#include <math.h>

#define M     1024
#define NB    16
#define NC    32
#define HF    256
#define WF    256
#define RH    8
#define MAXW  128
#define OUT0  (M * RH * MAXW * NC)   // 33,554,432 floats

typedef float    f4raw __attribute__((ext_vector_type(4)));  // nontemporal-store-compatible
typedef _Float16 h4    __attribute__((ext_vector_type(4)));
typedef _Float16 h8    __attribute__((ext_vector_type(8)));

struct BoxParam {
    float p1x, p1y;   // top-left corner (already /4)
    float axx, axy;   // per-x step
    float ayx, ayy;   // per-y step
    int   width;      // clipped int width
    int   n;          // feature-map batch index
};

// Geometry + exact width (must match numpy bit-exactly: no FMA contraction).
__device__ __forceinline__ int box_geom(
    const float* __restrict__ boxes, int i,
    float& x1, float& y1, float& dwx, float& dwy,
    float& dhx, float& dhy, float& wf)
{
    x1 = boxes[i * 8 + 0] * 0.25f; y1 = boxes[i * 8 + 1] * 0.25f;
    float x2 = boxes[i * 8 + 2] * 0.25f, y2 = boxes[i * 8 + 3] * 0.25f;
    float x4 = boxes[i * 8 + 6] * 0.25f, y4 = boxes[i * 8 + 7] * 0.25f;
    dwx = x2 - x1; dwy = y2 - y1;
    dhx = x4 - x1; dhy = y4 - y1;
    float bw2   = __fadd_rn(__fmul_rn(dwx, dwx), __fmul_rn(dwy, dwy));
    float bh2   = __fadd_rn(__fmul_rn(dhx, dhx), __fmul_rn(dhy, dhy));
    float box_w = __fsqrt_rn(bw2);
    float box_h = __fsqrt_rn(bh2);
    bool  swp = (box_w <= box_h);
    float bwv = swp ? box_h : box_w;
    float bhv = swp ? box_w : box_h;
    float ratio = __fdiv_rn(__fmul_rn(8.0f, bwv), fmaxf(bhv, 1e-6f));
    wf = fminf(fmaxf(ceilf(ratio), 1.0f), 128.0f);
    return (int)wf;
}

// ---------------------------------------------------------------------------
// Setup: 16 blocks x 256 threads; block b ranks boxes [b*64, b*64+64) with
// 4 threads per box, shuffle-reduced. Stable descending sort by width.
// ---------------------------------------------------------------------------
__global__ __launch_bounds__(256) void roi_setup_kernel(
    const float* __restrict__ boxes, const int* __restrict__ mapping,
    BoxParam* __restrict__ params, float* __restrict__ out_tail)
{
    __shared__ int s_w[M];
    const int t = threadIdx.x, b = blockIdx.x;

    #pragma unroll
    for (int r = 0; r < 4; ++r) {
        int i = r * 256 + t;
        float x1, y1, dwx, dwy, dhx, dhy, wf;
        s_w[i] = box_geom(boxes, i, x1, y1, dwx, dwy, dhx, dhy, wf);
    }
    __syncthreads();

    const int local = t >> 2;
    const int q     = t & 3;
    const int i     = b * 64 + local;
    const int w     = s_w[i];

    const int4* sw4 = (const int4*)(s_w + q * 256);
    int rank = 0;
    for (int j4 = 0; j4 < 64; ++j4) {
        int4 v = sw4[j4];
        int  j = q * 256 + j4 * 4;
        rank += (v.x > w) || ((v.x == w) && (j + 0 < i));
        rank += (v.y > w) || ((v.y == w) && (j + 1 < i));
        rank += (v.z > w) || ((v.z == w) && (j + 2 < i));
        rank += (v.w > w) || ((v.w == w) && (j + 3 < i));
    }
    rank += __shfl_down(rank, 1);
    rank += __shfl_down(rank, 2);

    if (q == 0) {
        float x1, y1, dwx, dwy, dhx, dhy, wf;
        box_geom(boxes, i, x1, y1, dwx, dwy, dhx, dhy, wf);
        BoxParam bp;
        bp.p1x = x1; bp.p1y = y1;
        bp.axx = __fdiv_rn(dwx, wf);  bp.axy = __fdiv_rn(dwy, wf);
        bp.ayx = dhx * 0.125f;        bp.ayy = dhy * 0.125f;
        bp.width = w;
        bp.n     = mapping[i];
        params[rank] = bp;
        out_tail[rank]     = wf;
        out_tail[M + rank] = (float)i;
    }
}

// ---------------------------------------------------------------------------
// Transpose NCHW fp32 -> NHWC fp16 via LDS tile, 4 y-rows per block.
// Block = (n, 4-row y-tile, 64-wide x-tile); grid = 16*64*4 = 4096.
// fp16 store halves the write stream (132 MB -> 66 MB); interpolation error
// from storage rounding <= ~6*2^-11 ~ 0.003, well under the 0.0156 bar.
// ---------------------------------------------------------------------------
#define YPB 4
__global__ __launch_bounds__(256) void roi_transpose_kernel(
    const float* __restrict__ fm, _Float16* __restrict__ fmT)
{
    __shared__ float tile[YPB][64][33];
    const int t  = threadIdx.x;
    const int xb = (blockIdx.x & 3) * 64;                 // 2 bits: x-tile
    const int y0 = ((blockIdx.x >> 2) & 63) * YPB;        // 6 bits: y-tile
    const int n  = blockIdx.x >> 8;                       // 4 bits: image

    const int c  = t >> 3;
    const int ws = t & 7;
    const int x0 = ws * 8;

    const float* src = fm + (((size_t)(n * NC + c) * HF + y0) * WF + xb + x0);
    float4 v0_0, v1_0, v0_1, v1_1, v0_2, v1_2, v0_3, v1_3;
    v0_0 = ((const float4*)(src + 0 * WF))[0];  v1_0 = ((const float4*)(src + 0 * WF))[1];
    v0_1 = ((const float4*)(src + 1 * WF))[0];  v1_1 = ((const float4*)(src + 1 * WF))[1];
    v0_2 = ((const float4*)(src + 2 * WF))[0];  v1_2 = ((const float4*)(src + 2 * WF))[1];
    v0_3 = ((const float4*)(src + 3 * WF))[0];  v1_3 = ((const float4*)(src + 3 * WF))[1];

    tile[0][x0+0][c]=v0_0.x; tile[0][x0+1][c]=v0_0.y; tile[0][x0+2][c]=v0_0.z; tile[0][x0+3][c]=v0_0.w;
    tile[0][x0+4][c]=v1_0.x; tile[0][x0+5][c]=v1_0.y; tile[0][x0+6][c]=v1_0.z; tile[0][x0+7][c]=v1_0.w;
    tile[1][x0+0][c]=v0_1.x; tile[1][x0+1][c]=v0_1.y; tile[1][x0+2][c]=v0_1.z; tile[1][x0+3][c]=v0_1.w;
    tile[1][x0+4][c]=v1_1.x; tile[1][x0+5][c]=v1_1.y; tile[1][x0+6][c]=v1_1.z; tile[1][x0+7][c]=v1_1.w;
    tile[2][x0+0][c]=v0_2.x; tile[2][x0+1][c]=v0_2.y; tile[2][x0+2][c]=v0_2.z; tile[2][x0+3][c]=v0_2.w;
    tile[2][x0+4][c]=v1_2.x; tile[2][x0+5][c]=v1_2.y; tile[2][x0+6][c]=v1_2.z; tile[2][x0+7][c]=v1_2.w;
    tile[3][x0+0][c]=v0_3.x; tile[3][x0+1][c]=v0_3.y; tile[3][x0+2][c]=v0_3.z; tile[3][x0+3][c]=v0_3.w;
    tile[3][x0+4][c]=v1_3.x; tile[3][x0+5][c]=v1_3.y; tile[3][x0+6][c]=v1_3.z; tile[3][x0+7][c]=v1_3.w;
    __syncthreads();

    const int xl = t >> 2;
    const int c0 = (t & 3) * 8;
    #pragma unroll
    for (int yy = 0; yy < YPB; ++yy) {
        _Float16* dst = fmT + (((size_t)(n * HF + y0 + yy) * WF + xb + xl) * NC + c0);
        h8 hv;
        hv[0] = (_Float16)tile[yy][xl][c0+0];
        hv[1] = (_Float16)tile[yy][xl][c0+1];
        hv[2] = (_Float16)tile[yy][xl][c0+2];
        hv[3] = (_Float16)tile[yy][xl][c0+3];
        hv[4] = (_Float16)tile[yy][xl][c0+4];
        hv[5] = (_Float16)tile[yy][xl][c0+5];
        hv[6] = (_Float16)tile[yy][xl][c0+6];
        hv[7] = (_Float16)tile[yy][xl][c0+7];
        *(h8*)dst = hv;
    }
}

// ---------------------------------------------------------------------------
// Main (NHWC fp16): block = (k,y) via blockIdx = y*1024+k. 1024%8==0 so all
// 8 rows of box k land on the same XCD (k%8). 256 threads = 32 x-positions
// x 8 channel-quads; a pixel's 32 channels = 64 B = ONE cache line.
// sx/sy bit-exact to numpy: (p1 + ax*x) + ay*y, no FMA contraction.
// Interpolation in fp32 after convert; output stores nontemporal.
// ---------------------------------------------------------------------------
__global__ __launch_bounds__(256) void roi_main_nhwc(
    const _Float16* __restrict__ fmT, const BoxParam* __restrict__ params,
    float* __restrict__ out)
{
    const int k = blockIdx.x & (M - 1);
    const int y = blockIdx.x >> 10;
    const BoxParam bp = params[k];     // block-uniform -> scalar loads

    const int t  = threadIdx.x;
    const int cg = (t & 7) * 4;        // channel quad
    const int xl = t >> 3;             // 0..31

    const _Float16* fmb  = fmT + (size_t)bp.n * (HF * WF * NC);
    float*          orow = out + ((size_t)(k * RH + y) * MAXW) * NC + cg;

    const float yf    = (float)y;
    const int   width = bp.width;
    const int   niter = (width + 31) >> 5;   // block-uniform trip count

    const float ayxy = __fmul_rn(bp.ayx, yf);
    const float ayyy = __fmul_rn(bp.ayy, yf);

    for (int xi = 0; xi < niter; ++xi) {
        const int x = xi * 32 + xl;
        float xf = (float)x;
        // numpy order: (p1 + ax*x) + ay*y, each op round-to-nearest
        float sx = __fadd_rn(__fadd_rn(bp.p1x, __fmul_rn(bp.axx, xf)), ayxy);
        float sy = __fadd_rn(__fadd_rn(bp.p1y, __fmul_rn(bp.axy, xf)), ayyy);
        float fx0 = floorf(sx), fy0 = floorf(sy);
        float tx = sx - fx0,    ty = sy - fy0;
        int ix0 = (int)fx0, iy0 = (int)fy0;
        int ix1 = ix0 + 1,  iy1 = iy0 + 1;

        float valid = (x < width) ? 1.0f : 0.0f;
        float mx0 = (ix0 >= 0 && ix0 < WF) ? valid : 0.0f;
        float mx1 = (ix1 >= 0 && ix1 < WF) ? valid : 0.0f;
        float my0 = (iy0 >= 0 && iy0 < HF) ? 1.0f : 0.0f;
        float my1 = (iy1 >= 0 && iy1 < HF) ? 1.0f : 0.0f;
        int xc0 = min(max(ix0, 0), WF - 1), xc1 = min(max(ix1, 0), WF - 1);
        int yc0 = min(max(iy0, 0), HF - 1), yc1 = min(max(iy1, 0), HF - 1);

        float omtx = 1.0f - tx, omty = 1.0f - ty;
        float q00 = omtx * omty * (mx0 * my0);
        float q01 = tx   * omty * (mx1 * my0);
        float q10 = omtx * ty   * (mx0 * my1);
        float q11 = tx   * ty   * (mx1 * my1);

        h4 v00 = *(const h4*)(fmb + (size_t)(yc0 * WF + xc0) * NC + cg);
        h4 v01 = *(const h4*)(fmb + (size_t)(yc0 * WF + xc1) * NC + cg);
        h4 v10 = *(const h4*)(fmb + (size_t)(yc1 * WF + xc0) * NC + cg);
        h4 v11 = *(const h4*)(fmb + (size_t)(yc1 * WF + xc1) * NC + cg);

        f4raw r;
        r.x = (float)v00[0] * q00 + (float)v01[0] * q01 + (float)v10[0] * q10 + (float)v11[0] * q11;
        r.y = (float)v00[1] * q00 + (float)v01[1] * q01 + (float)v10[1] * q10 + (float)v11[1] * q11;
        r.z = (float)v00[2] * q00 + (float)v01[2] * q01 + (float)v10[2] * q10 + (float)v11[2] * q11;
        r.w = (float)v00[3] * q00 + (float)v01[3] * q01 + (float)v10[3] * q10 + (float)v11[3] * q11;
        __builtin_nontemporal_store(r, (f4raw*)(orow + (size_t)x * NC));
    }
    // zero-fill remaining columns (col_mask; d_out is poisoned each launch)
    const f4raw z = {0.f, 0.f, 0.f, 0.f};
    for (int xi = niter; xi < MAXW / 32; ++xi) {
        const int x = xi * 32 + xl;
        __builtin_nontemporal_store(z, (f4raw*)(orow + (size_t)x * NC));
    }
}

// ---------------------------------------------------------------------------
// Fallback (NCHW direct gather, fp32) if d_ws can't hold the transposed map.
// ---------------------------------------------------------------------------
__global__ __launch_bounds__(256) void roi_main_nchw(
    const float* __restrict__ fm, const BoxParam* __restrict__ params,
    float* __restrict__ out)
{
    const int k = blockIdx.x & (M - 1);
    const int y = blockIdx.x >> 10;
    const BoxParam bp = params[k];

    const int c  = threadIdx.x & 31;
    const int xg = threadIdx.x >> 5;

    const float* fmc  = fm + ((size_t)(bp.n * NC + c)) * (size_t)(HF * WF);
    float*       orow = out + ((size_t)(k * RH + y) * MAXW) * NC + c;

    const float yf = (float)y;
    const float ayxy = __fmul_rn(bp.ayx, yf);
    const float ayyy = __fmul_rn(bp.ayy, yf);
    const int width = bp.width;
    const int niter = (width + 7) >> 3;

    for (int xi = 0; xi < niter; ++xi) {
        const int x = xi * 8 + xg;
        float xf = (float)x;
        float sx = __fadd_rn(__fadd_rn(bp.p1x, __fmul_rn(bp.axx, xf)), ayxy);
        float sy = __fadd_rn(__fadd_rn(bp.p1y, __fmul_rn(bp.axy, xf)), ayyy);
        float fx0 = floorf(sx), fy0 = floorf(sy);
        float tx = sx - fx0,    ty = sy - fy0;
        int ix0 = (int)fx0, iy0 = (int)fy0;
        int ix1 = ix0 + 1,  iy1 = iy0 + 1;
        float valid = (x < width) ? 1.0f : 0.0f;
        float mx0 = (ix0 >= 0 && ix0 < WF) ? valid : 0.0f;
        float mx1 = (ix1 >= 0 && ix1 < WF) ? valid : 0.0f;
        float my0 = (iy0 >= 0 && iy0 < HF) ? 1.0f : 0.0f;
        float my1 = (iy1 >= 0 && iy1 < HF) ? 1.0f : 0.0f;
        int xc0 = min(max(ix0, 0), WF - 1), xc1 = min(max(ix1, 0), WF - 1);
        int yc0 = min(max(iy0, 0), HF - 1), yc1 = min(max(iy1, 0), HF - 1);
        float omtx = 1.0f - tx, omty = 1.0f - ty;
        float q00 = omtx * omty * (mx0 * my0);
        float q01 = tx   * omty * (mx1 * my0);
        float q10 = omtx * ty   * (mx0 * my1);
        float q11 = tx   * ty   * (mx1 * my1);
        float val = fmc[yc0 * WF + xc0] * q00 + fmc[yc0 * WF + xc1] * q01
                  + fmc[yc1 * WF + xc0] * q10 + fmc[yc1 * WF + xc1] * q11;
        orow[(size_t)(x * NC)] = val;
    }
    for (int xi = niter; xi < 16; ++xi)
        orow[(size_t)((xi * 8 + xg) * NC)] = 0.0f;
}

// ---------------------------------------------------------------------------
extern "C" void kernel_launch(void* const* d_in, const int* in_sizes, int n_in,
                              void* d_out, int out_size, void* d_ws, size_t ws_size,
                              hipStream_t stream)
{
    const float* fm      = (const float*)d_in[0];
    const float* boxes   = (const float*)d_in[1];
    const int*   mapping = (const int*)d_in[2];
    float*       out     = (float*)d_out;

    BoxParam* params = (BoxParam*)d_ws;                       // 32 KB
    const size_t FMT_OFF = 65536;
    const size_t need = FMT_OFF + (size_t)NB * HF * WF * NC * sizeof(_Float16);

    roi_setup_kernel<<<16, 256, 0, stream>>>(boxes, mapping, params, out + OUT0);

    if (ws_size >= need) {
        _Float16* fmT = (_Float16*)((char*)d_ws + FMT_OFF);
        roi_transpose_kernel<<<NB * (HF / YPB) * (WF / 64), 256, 0, stream>>>(fm, fmT);
        roi_main_nhwc<<<M * RH, 256, 0, stream>>>(fmT, params, out);
    } else {
        roi_main_nchw<<<M * RH, 256, 0, stream>>>(fm, params, out);
    }
}